// Round 5
// baseline (911.633 us; speedup 1.0000x reference)
//
#include <hip/hip_runtime.h>

#define NTOK 8192     // B*S
#define DDIM 1024
#define FDIM 4096
#define NEXP 8
#define TDIM 64
#define MAXBLK 72     // max sum_e ceil(cnt_e/256) = 64+8

// ws layout:
#define H_OFF   (1u<<20)
#define W1B_OFF (H_OFF + 134217728u)      // H: 16384 x 4096 bf16 = 128 MiB
#define W2B_OFF (W1B_OFF + 67108864u)     // W1b: 64 MiB
#define XB_OFF  (W2B_OFF + 67108864u)     // W2b: 64 MiB
#define FULL_WS (XB_OFF + 16777216u)      // Xb: 16 MiB

typedef __bf16 bf16x8 __attribute__((ext_vector_type(8)));
typedef unsigned short u16x8 __attribute__((ext_vector_type(8)));
typedef unsigned short u16x4 __attribute__((ext_vector_type(4)));
typedef float f32x4 __attribute__((ext_vector_type(4)));

__device__ __forceinline__ float gelu_tanh(float h) {
  float u = 0.7978845608028654f * (h + 0.044715f * h * h * h);
  float e = __expf(2.0f * u);
  return 0.5f * h * (2.0f - 2.0f / (e + 1.0f));
}

__device__ __forceinline__ void glds16(const void* g, void* l) {
  __builtin_amdgcn_global_load_lds((const __attribute__((address_space(1))) void*)g,
                                   (__attribute__((address_space(3))) void*)l, 16, 0, 0);
}

#define VM8() asm volatile("s_waitcnt vmcnt(8)" ::: "memory")
#define VM4() asm volatile("s_waitcnt vmcnt(4)" ::: "memory")
#define VM0() asm volatile("s_waitcnt vmcnt(0)" ::: "memory")
#define BAR() __builtin_amdgcn_s_barrier()

// ---------------- gating ----------------
__global__ __launch_bounds__(256) void gate_kernel(
    const float* __restrict__ x, const float* __restrict__ task,
    const float* __restrict__ alpha_p,
    const float* __restrict__ Wg_in, const float* __restrict__ bg_in,
    const float* __restrict__ Wg_task, const float* __restrict__ bg_task,
    int* __restrict__ cnt, float* __restrict__ wsum,
    int* __restrict__ tok_list, float* __restrict__ wt_list)
{
  __shared__ float s_wsum[NEXP];
  int tid = threadIdx.x;
  if (tid < NEXP) s_wsum[tid] = 0.0f;
  __syncthreads();

  int lane = tid & 63;
  int wid  = tid >> 6;
  int tok  = blockIdx.x * 4 + wid;
  float a  = alpha_p[0];

  const float* xr = x + (size_t)tok * DDIM;
  float accd[8] = {0,0,0,0,0,0,0,0};
#pragma unroll
  for (int i = 0; i < DDIM/64; ++i) {
    int d = lane + 64*i;
    float xv = xr[d];
    f32x4 wa = *(const f32x4*)(Wg_in + (size_t)d*8);
    f32x4 wb = *(const f32x4*)(Wg_in + (size_t)d*8 + 4);
#pragma unroll
    for (int j = 0; j < 4; ++j) {
      accd[j]   = fmaf(xv, wa[j], accd[j]);
      accd[4+j] = fmaf(xv, wb[j], accd[4+j]);
    }
  }
  float part[8];
  {
    int d = lane;
    float tv = task[(size_t)tok*TDIM + d];
    f32x4 wa = *(const f32x4*)(Wg_task + (size_t)d*8);
    f32x4 wb = *(const f32x4*)(Wg_task + (size_t)d*8 + 4);
#pragma unroll
    for (int j = 0; j < 4; ++j) {
      part[j]   = (1.0f-a)*accd[j]   + a*(tv*wa[j]);
      part[4+j] = (1.0f-a)*accd[4+j] + a*(tv*wb[j]);
    }
  }
#pragma unroll
  for (int e = 0; e < 8; ++e) {
#pragma unroll
    for (int m = 1; m < 64; m <<= 1) part[e] += __shfl_xor(part[e], m);
  }

  if (lane == 0) {
    float lg[8];
#pragma unroll
    for (int e = 0; e < 8; ++e) lg[e] = part[e] + (1.0f-a)*bg_in[e] + a*bg_task[e];
    int e0 = 0;
#pragma unroll
    for (int e = 1; e < 8; ++e) if (lg[e] > lg[e0]) e0 = e;
    int e1 = (e0 == 0) ? 1 : 0;
#pragma unroll
    for (int e = 0; e < 8; ++e) if (e != e0 && lg[e] > lg[e1]) e1 = e;
    float mx = lg[0];
#pragma unroll
    for (int e = 1; e < 8; ++e) mx = fmaxf(mx, lg[e]);
    float p[8], s = 0.0f;
#pragma unroll
    for (int e = 0; e < 8; ++e) { p[e] = __expf(lg[e] - mx); s += p[e]; }
    float inv = 1.0f / s;
#pragma unroll
    for (int e = 0; e < 8; ++e) atomicAdd(&s_wsum[e], p[e] * inv);
    float p1 = __expf(lg[e1] - lg[e0]);
    float w0 = 1.0f / (1.0f + p1);
    float w1 = p1 * w0;
    int pos0 = atomicAdd(&cnt[e0], 1);
    tok_list[e0*NTOK + pos0] = tok; wt_list[e0*NTOK + pos0] = w0;
    int pos1 = atomicAdd(&cnt[e1], 1);
    tok_list[e1*NTOK + pos1] = tok; wt_list[e1*NTOK + pos1] = w1;
  }
  __syncthreads();
  if (tid < NEXP) atomicAdd(&wsum[tid], s_wsum[tid]);
}

// ---------------- finalize: offsets + l_aux + block table ----------------
__global__ void finalize_kernel(const int* __restrict__ cnt, const float* __restrict__ wsum,
                                int* __restrict__ offs, float* __restrict__ laux,
                                int* __restrict__ blk_e, int* __restrict__ blk_m)
{
  if (threadIdx.x == 0) {
    int o = 0; float l = 0.0f; int nb = 0;
    for (int e = 0; e < NEXP; ++e) {
      offs[e] = o;
      for (int m0 = 0; m0 < cnt[e]; m0 += 256) {
        if (nb < MAXBLK) { blk_e[nb] = e; blk_m[nb] = m0; ++nb; }
      }
      l += (wsum[e] * (1.0f/NTOK)) * ((float)cnt[e] * (1.0f/NTOK));
      o += cnt[e];
    }
    for (; nb < MAXBLK; ++nb) blk_e[nb] = -1;
    *laux = l;
  }
}

// ---------------- prep: X -> bf16 ----------------
__global__ __launch_bounds__(256) void prep_x(const float* __restrict__ X,
                                              unsigned short* __restrict__ Xb)
{
  size_t i = ((size_t)blockIdx.x*256 + threadIdx.x)*8;
  f32x4 a = *(const f32x4*)(X + i);
  f32x4 b = *(const f32x4*)(X + i + 4);
  u16x8 v;
#pragma unroll
  for (int j = 0; j < 4; ++j) {
    v[j]   = __builtin_bit_cast(unsigned short, (__bf16)a[j]);
    v[4+j] = __builtin_bit_cast(unsigned short, (__bf16)b[j]);
  }
  *(u16x8*)(Xb + i) = v;
}

// ---------------- prep: W -> bf16, [n][k] 32-k granule tiles 256x32, paired rows --
// Granule tile (e,J,kt): 16KB, 1024 chunks. Chunk cl: R=cl>>3, d=(cl&7)^(R&7),
// n = J*256 + (R<<1)|(d>>2), phys k = kt*32 + (d&3)*8 + j.
// PERM (W2): source k within each 64-group = ((p&3)<<4)|(p>>2)  (H col order).
template<bool PERM>
__global__ __launch_bounds__(256) void prep_w(const float* __restrict__ W,
                                              unsigned short* __restrict__ Wb,
                                              int N, int NKB, int NJ)
{
  int kb = blockIdx.x, J = blockIdx.y, e = blockIdx.z;
  int K = NKB*64;
  __shared__ unsigned short t[64*264];
  int tid = threadIdx.x;
  const float* src = W + ((size_t)e*K + (size_t)kb*64) * N + J*256;
  int k = tid >> 2, cg = tid & 3;
#pragma unroll
  for (int ii = 0; ii < 16; ++ii) {
    int n = cg*64 + ii*4;
    f32x4 v = *(const f32x4*)(src + (size_t)k*N + n);
    u16x4 b;
#pragma unroll
    for (int j = 0; j < 4; ++j) b[j] = __builtin_bit_cast(unsigned short, (__bf16)v[j]);
    *(u16x4*)&t[k*264 + n] = b;
  }
  __syncthreads();
  unsigned short* dst = Wb + ((size_t)(e*NJ + J)*NKB + kb)*16384;
#pragma unroll
  for (int i = 0; i < 8; ++i) {
    int c2 = i*256 + tid;            // [0,2048): two 16KB granule tiles
    int cl = c2 & 1023;
    int h  = c2 >> 10;
    int R  = cl >> 3, dp = cl & 7;
    int d  = dp ^ (R & 7);
    int nloc = (R<<1) | (d>>2);
    int pbase = h*32 + (d&3)*8;
    u16x8 v;
#pragma unroll
    for (int j = 0; j < 8; ++j) {
      int v64 = pbase + j;
      int kl  = PERM ? (((v64 & 3) << 4) | (v64 >> 2)) : v64;
      v[j] = t[kl*264 + nloc];
    }
    *(u16x8*)(dst + (size_t)c2*8) = v;
  }
}

// ================== ring-4 deep-pipelined 256x256 GEMMs (BK=32) ==================
// 8 waves (2M x 4N), per-wave C=128x64 (acc[8][4]), 32 MFMA / K-tile / wave.
// 4 LDS buffers x (16KB A + 16KB B) = 128 KB. Prefetch depth 3, counted vmcnt(8),
// one raw s_barrier per K-tile. STAGE = 4 glds16/thread.

#define STAGE(bufbase, t) do {                                                \
  char* sa__ = ldsb + (bufbase);                                              \
  _Pragma("unroll")                                                           \
  for (int i_ = 0; i_ < 2; ++i_) {                                            \
    glds16(asrc[i_] + (size_t)(t)*64, sa__ + dstoff[i_]);                     \
    glds16(bsrc + (size_t)(t)*16384 + i_*8192, sa__ + 16384 + dstoff[i_]);    \
  }                                                                           \
} while (0)

#define COMPUTE(bufbase) do {                                                 \
  const unsigned short* sa_ = (const unsigned short*)(ldsb + (bufbase));      \
  const unsigned short* sb_ = sa_ + 8192;                                     \
  bf16x8 bfv_[4];                                                             \
  _Pragma("unroll")                                                           \
  for (int ni_ = 0; ni_ < 4; ++ni_)                                           \
    bfv_[ni_] = *(const bf16x8*)&sb_[boff0 + ni_*512];                        \
  __builtin_amdgcn_s_setprio(1);                                              \
  _Pragma("unroll")                                                           \
  for (int mi_ = 0; mi_ < 8; ++mi_) {                                         \
    bf16x8 af_ = *(const bf16x8*)&sa_[aoff0 + mi_*512];                       \
    _Pragma("unroll")                                                         \
    for (int ni_ = 0; ni_ < 4; ++ni_)                                         \
      acc[mi_][ni_] = __builtin_amdgcn_mfma_f32_16x16x32_bf16(af_, bfv_[ni_], acc[mi_][ni_], 0, 0, 0); \
  }                                                                           \
  __builtin_amdgcn_s_setprio(0);                                              \
} while (0)

// ---------------- GEMM1: H = gelu(gather(Xb) @ W1b + b1) ----------------
__global__ __launch_bounds__(512) void gemm1_v5(
    const unsigned short* __restrict__ Xb, const unsigned short* __restrict__ W1b,
    const float* __restrict__ b1,
    const int* __restrict__ cnt, const int* __restrict__ offs,
    const int* __restrict__ tok_list,
    const int* __restrict__ blk_e, const int* __restrict__ blk_m,
    unsigned short* __restrict__ H)
{
  int e = blk_e[blockIdx.y];
  if (e < 0) return;
  int m0 = blk_m[blockIdx.y];
  int ce = cnt[e];
  int off = offs[e];
  int J = blockIdx.x;

  __shared__ __align__(16) char ldsb[131072];
  __shared__ int s_tok[256];

  int tid = threadIdx.x;
  if (tid < 256) {
    int idx = m0 + tid;
    s_tok[tid] = tok_list[e*NTOK + ((idx < ce) ? idx : (ce-1))];
  }
  __syncthreads();

  int l = tid & 63, w = tid >> 6;
  int wr = w >> 2, wc = w & 3;
  int q = l & 15, g = l >> 4;

  const char* asrc[2];
  int dstoff[2];
#pragma unroll
  for (int i = 0; i < 2; ++i) {
    int c = i*512 + tid;
    int R = c >> 3, dp = c & 7;
    int d = dp ^ (R & 7);
    int r = (R << 1) | (d >> 2);
    int kc = d & 3;
    asrc[i] = (const char*)(Xb + (size_t)s_tok[r]*DDIM) + kc*16;
    dstoff[i] = c*16;
  }
  const char* bsrc = (const char*)W1b + (size_t)((e*16 + J)*32) * 16384 + (size_t)tid*16;

  // fragment LDS offsets (ushort units): row-paired layout
  int rowA = wr*128 + q, rowB = wc*64 + q;
  int RA = rowA >> 1, RB = rowB >> 1;
  int dq = ((q & 1) << 2) | g;
  const int aoff0 = RA*64 + (dq ^ (RA & 7))*8;
  const int boff0 = RB*64 + (dq ^ (RB & 7))*8;

  f32x4 acc[8][4];
#pragma unroll
  for (int mi = 0; mi < 8; ++mi)
#pragma unroll
    for (int ni = 0; ni < 4; ++ni) acc[mi][ni] = (f32x4){0.f,0.f,0.f,0.f};

#define NT1 (DDIM/32)
  STAGE(0, 0); STAGE(32768, 1); STAGE(65536, 2);
  VM8(); BAR();
  for (int t = 0; t < NT1-3; ++t) {
    STAGE(((t+3)&3)*32768, t+3);
    COMPUTE((t&3)*32768);
    VM8(); BAR();
  }
  COMPUTE(((NT1-3)&3)*32768); VM4(); BAR();
  COMPUTE(((NT1-2)&3)*32768); VM0(); BAR();
  COMPUTE(((NT1-1)&3)*32768);

  // epilogue: bias+gelu, permuted H col order (phys = base + q*4 + ni)
  int n0 = J*256;
  float bias[4];
#pragma unroll
  for (int ni = 0; ni < 4; ++ni) bias[ni] = b1[(size_t)e*FDIM + n0 + wc*64 + ni*16 + q];
#pragma unroll
  for (int mi = 0; mi < 8; ++mi) {
#pragma unroll
    for (int j = 0; j < 4; ++j) {
      int r = wr*128 + mi*16 + g*4 + j;
      if (m0 + r >= ce) continue;
      u16x4 hv;
#pragma unroll
      for (int ni = 0; ni < 4; ++ni) {
        float h = acc[mi][ni][j] + bias[ni];
        hv[ni] = __builtin_bit_cast(unsigned short, (__bf16)gelu_tanh(h));
      }
      *(u16x4*)&H[(size_t)(off + m0 + r)*FDIM + n0 + wc*64 + q*4] = hv;
    }
  }
}

// ---------------- GEMM2: out[tok] += w * (H @ W2b + b2), split-K x2 -------------
__global__ __launch_bounds__(512) void gemm2_v5(
    const unsigned short* __restrict__ H, const unsigned short* __restrict__ W2b,
    const float* __restrict__ b2,
    const int* __restrict__ cnt, const int* __restrict__ offs,
    const int* __restrict__ tok_list, const float* __restrict__ wt_list,
    const int* __restrict__ blk_e, const int* __restrict__ blk_m,
    float* __restrict__ out)
{
  int e = blk_e[blockIdx.y];
  if (e < 0) return;
  int m0 = blk_m[blockIdx.y];
  int ce = cnt[e];
  int off = offs[e];
  int J = blockIdx.x;
  int s = blockIdx.z;                // K-split: phys H cols [s*2048, s*2048+2048)

  __shared__ __align__(16) char ldsb[131072];
  __shared__ int   s_tok[256];
  __shared__ float s_wt[256];

  int tid = threadIdx.x;
  if (tid < 256) {
    int idx = m0 + tid;
    int cidx = (idx < ce) ? idx : (ce-1);
    s_tok[tid] = tok_list[e*NTOK + cidx];
    s_wt[tid]  = (idx < ce) ? wt_list[e*NTOK + cidx] : 0.0f;
  }
  __syncthreads();

  int l = tid & 63, w = tid >> 6;
  int wr = w >> 2, wc = w & 3;
  int q = l & 15, g = l >> 4;

  const char* asrc[2];
  int dstoff[2];
#pragma unroll
  for (int i = 0; i < 2; ++i) {
    int c = i*512 + tid;
    int R = c >> 3, dp = c & 7;
    int d = dp ^ (R & 7);
    int r = (R << 1) | (d >> 2);
    int kc = d & 3;
    int rr = (m0 + r < ce) ? r : (ce-1-m0);
    asrc[i] = (const char*)(H + (size_t)(off + m0 + rr)*FDIM) + kc*16 + s*4096;
    dstoff[i] = c*16;
  }
  const char* bsrc = (const char*)W2b + (size_t)((e*4 + J)*128 + s*64) * 16384 + (size_t)tid*16;

  int rowA = wr*128 + q, rowB = wc*64 + q;
  int RA = rowA >> 1, RB = rowB >> 1;
  int dq = ((q & 1) << 2) | g;
  const int aoff0 = RA*64 + (dq ^ (RA & 7))*8;
  const int boff0 = RB*64 + (dq ^ (RB & 7))*8;

  f32x4 acc[8][4];
#pragma unroll
  for (int mi = 0; mi < 8; ++mi)
#pragma unroll
    for (int ni = 0; ni < 4; ++ni) acc[mi][ni] = (f32x4){0.f,0.f,0.f,0.f};

#define NT2 (FDIM/32/2)
  STAGE(0, 0); STAGE(32768, 1); STAGE(65536, 2);
  VM8(); BAR();
  for (int t = 0; t < NT2-3; ++t) {
    STAGE(((t+3)&3)*32768, t+3);
    COMPUTE((t&3)*32768);
    VM8(); BAR();
  }
  COMPUTE(((NT2-3)&3)*32768); VM4(); BAR();
  COMPUTE(((NT2-2)&3)*32768); VM0(); BAR();
  COMPUTE(((NT2-1)&3)*32768);

  int n0 = J*256;
  float bias[4];
#pragma unroll
  for (int ni = 0; ni < 4; ++ni)
    bias[ni] = (s == 0) ? b2[(size_t)e*DDIM + n0 + wc*64 + ni*16 + q] : 0.0f;
#pragma unroll
  for (int mi = 0; mi < 8; ++mi) {
#pragma unroll
    for (int j = 0; j < 4; ++j) {
      int r = wr*128 + mi*16 + g*4 + j;
      if (m0 + r >= ce) continue;
      int tok = s_tok[r];
      float wt = s_wt[r];
      float* orow = out + (size_t)tok * DDIM;
#pragma unroll
      for (int ni = 0; ni < 4; ++ni) {
        float y = acc[mi][ni][j] + bias[ni];
        unsafeAtomicAdd(&orow[n0 + wc*64 + ni*16 + q], wt * y);
      }
    }
  }
}

// ---------------- launch ----------------
extern "C" void kernel_launch(void* const* d_in, const int* in_sizes, int n_in,
                              void* d_out, int out_size, void* d_ws, size_t ws_size,
                              hipStream_t stream)
{
  const float* x       = (const float*)d_in[0];
  const float* task    = (const float*)d_in[1];
  const float* alpha   = (const float*)d_in[2];
  const float* Wg_in   = (const float*)d_in[3];
  const float* bg_in   = (const float*)d_in[4];
  const float* Wg_task = (const float*)d_in[5];
  const float* bg_task = (const float*)d_in[6];
  const float* W1      = (const float*)d_in[7];
  const float* b1      = (const float*)d_in[8];
  const float* W2      = (const float*)d_in[9];
  const float* b2      = (const float*)d_in[10];
  float* out = (float*)d_out;

  char* ws = (char*)d_ws;
  int*   cnt      = (int*)(ws + 0);
  float* wsum     = (float*)(ws + 32);
  int*   offs     = (int*)(ws + 64);
  int*   blk_e    = (int*)(ws + 128);
  int*   blk_m    = (int*)(ws + 512);
  int*   tok_list = (int*)(ws + 4096);
  float* wt_list  = (float*)(ws + 4096 + NTOK*NEXP*4);
  unsigned short* H   = (unsigned short*)(ws + H_OFF);
  unsigned short* W1b = (unsigned short*)(ws + W1B_OFF);
  unsigned short* W2b = (unsigned short*)(ws + W2B_OFF);
  unsigned short* Xb  = (unsigned short*)(ws + XB_OFF);

  hipMemsetAsync(d_out, 0, (size_t)out_size * sizeof(float), stream);
  hipMemsetAsync(ws, 0, 128, stream);
  gate_kernel<<<NTOK/4, 256, 0, stream>>>(x, task, alpha, Wg_in, bg_in, Wg_task, bg_task,
                                          cnt, wsum, tok_list, wt_list);
  finalize_kernel<<<1, 64, 0, stream>>>(cnt, wsum, offs, out + (size_t)NTOK*DDIM, blk_e, blk_m);
  prep_x<<<NTOK*DDIM/2048, 256, 0, stream>>>(x, Xb);
  prep_w<false><<<dim3(16, 16, NEXP), 256, 0, stream>>>(W1, W1b, FDIM, 16, 16);
  prep_w<true ><<<dim3(64,  4, NEXP), 256, 0, stream>>>(W2, W2b, DDIM, 64, 4);
  gemm1_v5<<<dim3(16, MAXBLK), 512, 0, stream>>>(Xb, W1b, b1, cnt, offs, tok_list,
                                                 blk_e, blk_m, H);
  gemm2_v5<<<dim3(4, MAXBLK, 2), 512, 0, stream>>>(H, W2b, b2, cnt, offs, tok_list, wt_list,
                                                   blk_e, blk_m, out);
}

// Round 6
// 855.973 us; speedup vs baseline: 1.0650x; 1.0650x over previous
//
#include <hip/hip_runtime.h>

#define NTOK 8192     // B*S
#define DDIM 1024
#define FDIM 4096
#define NEXP 8
#define TDIM 64
#define MAXBLK 72     // max sum_e ceil(cnt_e/256) = 64+8

// ws layout:
#define H_OFF   (1u<<20)
#define W1B_OFF (H_OFF + 134217728u)      // H: 16384 x 4096 bf16 = 128 MiB
#define W2B_OFF (W1B_OFF + 67108864u)     // W1b: 64 MiB
#define XB_OFF  (W2B_OFF + 67108864u)     // W2b: 64 MiB
#define FULL_WS (XB_OFF + 16777216u)      // Xb: 16 MiB

typedef __bf16 bf16x8 __attribute__((ext_vector_type(8)));
typedef unsigned short u16x8 __attribute__((ext_vector_type(8)));
typedef unsigned short u16x4 __attribute__((ext_vector_type(4)));
typedef float f32x4 __attribute__((ext_vector_type(4)));

__device__ __forceinline__ float gelu_tanh(float h) {
  float u = 0.7978845608028654f * (h + 0.044715f * h * h * h);
  float e = __expf(2.0f * u);
  return 0.5f * h * (2.0f - 2.0f / (e + 1.0f));
}

__device__ __forceinline__ void glds16(const void* g, void* l) {
  __builtin_amdgcn_global_load_lds((const __attribute__((address_space(1))) void*)g,
                                   (__attribute__((address_space(3))) void*)l, 16, 0, 0);
}

#define VM4() asm volatile("s_waitcnt vmcnt(4)" ::: "memory")
#define VM0() asm volatile("s_waitcnt vmcnt(0)" ::: "memory")

// ---------------- gating ----------------
__global__ __launch_bounds__(256) void gate_kernel(
    const float* __restrict__ x, const float* __restrict__ task,
    const float* __restrict__ alpha_p,
    const float* __restrict__ Wg_in, const float* __restrict__ bg_in,
    const float* __restrict__ Wg_task, const float* __restrict__ bg_task,
    int* __restrict__ cnt, float* __restrict__ wsum,
    int* __restrict__ tok_list, float* __restrict__ wt_list)
{
  __shared__ float s_wsum[NEXP];
  int tid = threadIdx.x;
  if (tid < NEXP) s_wsum[tid] = 0.0f;
  __syncthreads();

  int lane = tid & 63;
  int wid  = tid >> 6;
  int tok  = blockIdx.x * 4 + wid;
  float a  = alpha_p[0];

  const float* xr = x + (size_t)tok * DDIM;
  float accd[8] = {0,0,0,0,0,0,0,0};
#pragma unroll
  for (int i = 0; i < DDIM/64; ++i) {
    int d = lane + 64*i;
    float xv = xr[d];
    f32x4 wa = *(const f32x4*)(Wg_in + (size_t)d*8);
    f32x4 wb = *(const f32x4*)(Wg_in + (size_t)d*8 + 4);
#pragma unroll
    for (int j = 0; j < 4; ++j) {
      accd[j]   = fmaf(xv, wa[j], accd[j]);
      accd[4+j] = fmaf(xv, wb[j], accd[4+j]);
    }
  }
  float part[8];
  {
    int d = lane;
    float tv = task[(size_t)tok*TDIM + d];
    f32x4 wa = *(const f32x4*)(Wg_task + (size_t)d*8);
    f32x4 wb = *(const f32x4*)(Wg_task + (size_t)d*8 + 4);
#pragma unroll
    for (int j = 0; j < 4; ++j) {
      part[j]   = (1.0f-a)*accd[j]   + a*(tv*wa[j]);
      part[4+j] = (1.0f-a)*accd[4+j] + a*(tv*wb[j]);
    }
  }
#pragma unroll
  for (int e = 0; e < 8; ++e) {
#pragma unroll
    for (int m = 1; m < 64; m <<= 1) part[e] += __shfl_xor(part[e], m);
  }

  if (lane == 0) {
    float lg[8];
#pragma unroll
    for (int e = 0; e < 8; ++e) lg[e] = part[e] + (1.0f-a)*bg_in[e] + a*bg_task[e];
    int e0 = 0;
#pragma unroll
    for (int e = 1; e < 8; ++e) if (lg[e] > lg[e0]) e0 = e;
    int e1 = (e0 == 0) ? 1 : 0;
#pragma unroll
    for (int e = 0; e < 8; ++e) if (e != e0 && lg[e] > lg[e1]) e1 = e;
    float mx = lg[0];
#pragma unroll
    for (int e = 1; e < 8; ++e) mx = fmaxf(mx, lg[e]);
    float p[8], s = 0.0f;
#pragma unroll
    for (int e = 0; e < 8; ++e) { p[e] = __expf(lg[e] - mx); s += p[e]; }
    float inv = 1.0f / s;
#pragma unroll
    for (int e = 0; e < 8; ++e) atomicAdd(&s_wsum[e], p[e] * inv);
    float p1 = __expf(lg[e1] - lg[e0]);
    float w0 = 1.0f / (1.0f + p1);
    float w1 = p1 * w0;
    int pos0 = atomicAdd(&cnt[e0], 1);
    tok_list[e0*NTOK + pos0] = tok; wt_list[e0*NTOK + pos0] = w0;
    int pos1 = atomicAdd(&cnt[e1], 1);
    tok_list[e1*NTOK + pos1] = tok; wt_list[e1*NTOK + pos1] = w1;
  }
  __syncthreads();
  if (tid < NEXP) atomicAdd(&wsum[tid], s_wsum[tid]);
}

// ---------------- finalize: offsets + l_aux + block table ----------------
__global__ void finalize_kernel(const int* __restrict__ cnt, const float* __restrict__ wsum,
                                int* __restrict__ offs, float* __restrict__ laux,
                                int* __restrict__ blk_e, int* __restrict__ blk_m)
{
  if (threadIdx.x == 0) {
    int o = 0; float l = 0.0f; int nb = 0;
    for (int e = 0; e < NEXP; ++e) {
      offs[e] = o;
      for (int m0 = 0; m0 < cnt[e]; m0 += 256) {
        if (nb < MAXBLK) { blk_e[nb] = e; blk_m[nb] = m0; ++nb; }
      }
      l += (wsum[e] * (1.0f/NTOK)) * ((float)cnt[e] * (1.0f/NTOK));
      o += cnt[e];
    }
    for (; nb < MAXBLK; ++nb) blk_e[nb] = -1;
    *laux = l;
  }
}

// ---------------- prep: X -> bf16 ----------------
__global__ __launch_bounds__(256) void prep_x(const float* __restrict__ X,
                                              unsigned short* __restrict__ Xb)
{
  size_t i = ((size_t)blockIdx.x*256 + threadIdx.x)*8;
  f32x4 a = *(const f32x4*)(X + i);
  f32x4 b = *(const f32x4*)(X + i + 4);
  u16x8 v;
#pragma unroll
  for (int j = 0; j < 4; ++j) {
    v[j]   = __builtin_bit_cast(unsigned short, (__bf16)a[j]);
    v[4+j] = __builtin_bit_cast(unsigned short, (__bf16)b[j]);
  }
  *(u16x8*)(Xb + i) = v;
}

// ---------------- prep: W -> bf16, [n][k] 32-k granule tiles 256x32, paired rows --
// Granule tile (e,J,kt): 16KB, 1024 chunks. Chunk cl: R=cl>>3, d=(cl&7)^(R&7),
// n = J*256 + (R<<1)|(d>>2), phys k = kt*32 + (d&3)*8 + j.
// PERM (W2): source k within each 64-group = ((p&3)<<4)|(p>>2)  (H col order).
template<bool PERM>
__global__ __launch_bounds__(256) void prep_w(const float* __restrict__ W,
                                              unsigned short* __restrict__ Wb,
                                              int N, int NKB, int NJ)
{
  int kb = blockIdx.x, J = blockIdx.y, e = blockIdx.z;
  int K = NKB*64;
  __shared__ unsigned short t[64*264];
  int tid = threadIdx.x;
  const float* src = W + ((size_t)e*K + (size_t)kb*64) * N + J*256;
  int k = tid >> 2, cg = tid & 3;
#pragma unroll
  for (int ii = 0; ii < 16; ++ii) {
    int n = cg*64 + ii*4;
    f32x4 v = *(const f32x4*)(src + (size_t)k*N + n);
    u16x4 b;
#pragma unroll
    for (int j = 0; j < 4; ++j) b[j] = __builtin_bit_cast(unsigned short, (__bf16)v[j]);
    *(u16x4*)&t[k*264 + n] = b;
  }
  __syncthreads();
  unsigned short* dst = Wb + ((size_t)(e*NJ + J)*NKB + kb)*16384;
#pragma unroll
  for (int i = 0; i < 8; ++i) {
    int c2 = i*256 + tid;            // [0,2048): two 16KB granule tiles
    int cl = c2 & 1023;
    int h  = c2 >> 10;
    int R  = cl >> 3, dp = cl & 7;
    int d  = dp ^ (R & 7);
    int nloc = (R<<1) | (d>>2);
    int pbase = h*32 + (d&3)*8;
    u16x8 v;
#pragma unroll
    for (int j = 0; j < 8; ++j) {
      int v64 = pbase + j;
      int kl  = PERM ? (((v64 & 3) << 4) | (v64 >> 2)) : v64;
      v[j] = t[kl*264 + nloc];
    }
    *(u16x8*)(dst + (size_t)c2*8) = v;
  }
}

// ================== 8-phase 256x256 GEMMs (BK=64, m201 template) ==================
// 8 waves (2M x 4N), per-wave C=128x64 (acc[8][4]). LDS: A 4x16KB granules +
// B 4x16KB granules = 128KB. Tile t = granules (2t,2t+1). Per tile 4 phases:
// ph1 kk0/mi0-3(+B), ph2 kk0/mi4-7, ph3 kk1/mi0-3(+B), ph4 kk1/mi4-7.
// Stage 1 granule per phase; counted vmcnt(4) once per tile (never 0 mid-loop).

#define AG(b,kh) (ldsb + (((b)*2+(kh))<<14))
#define BG(b,kh) (ldsb + 65536 + (((b)*2+(kh))<<14))

#define STAGE_A(b,kh,gi) do { char* dA_ = AG(b,kh);                        \
  glds16(asrc0 + (size_t)(gi)*64, dA_ + dstoff0);                          \
  glds16(asrc1 + (size_t)(gi)*64, dA_ + dstoff1); } while (0)

#define STAGE_B(b,kh,gi) do { char* dB_ = BG(b,kh);                        \
  glds16(bsrc + (size_t)(gi)*16384,        dB_ + dstoff0);                 \
  glds16(bsrc + (size_t)(gi)*16384 + 8192, dB_ + dstoff1); } while (0)

#define PHASE(SA, SB, MIBASE, READB, STAGE_STMT, VM_STMT) do {              \
  const unsigned short* sa_ = (const unsigned short*)(SA);                  \
  bf16x8 af_[4];                                                            \
  _Pragma("unroll")                                                         \
  for (int i_ = 0; i_ < 4; ++i_)                                            \
    af_[i_] = *(const bf16x8*)&sa_[aoff0 + (MIBASE + i_)*512];              \
  if (READB) {                                                              \
    const unsigned short* sb_ = (const unsigned short*)(SB);                \
    _Pragma("unroll")                                                       \
    for (int ni_ = 0; ni_ < 4; ++ni_)                                       \
      bfv[ni_] = *(const bf16x8*)&sb_[boff0 + ni_*512];                     \
  }                                                                         \
  STAGE_STMT;                                                               \
  VM_STMT;                                                                  \
  __builtin_amdgcn_s_barrier();                                             \
  asm volatile("s_waitcnt lgkmcnt(0)" ::: "memory");                        \
  __builtin_amdgcn_sched_barrier(0);                                        \
  __builtin_amdgcn_s_setprio(1);                                            \
  _Pragma("unroll")                                                         \
  for (int i_ = 0; i_ < 4; ++i_)                                            \
    _Pragma("unroll")                                                       \
    for (int ni_ = 0; ni_ < 4; ++ni_)                                       \
      acc[MIBASE + i_][ni_] = __builtin_amdgcn_mfma_f32_16x16x32_bf16(      \
          af_[i_], bfv[ni_], acc[MIBASE + i_][ni_], 0, 0, 0);               \
  __builtin_amdgcn_s_setprio(0);                                            \
  __builtin_amdgcn_s_barrier();                                             \
} while (0)

#define KLOOP(NT) do {                                                      \
  STAGE_A(0,0,0); STAGE_B(0,0,0);                                           \
  STAGE_A(0,1,1); STAGE_B(0,1,1);                                           \
  STAGE_A(1,0,2); STAGE_B(1,0,2);                                           \
  VM4();                                                                    \
  __builtin_amdgcn_s_barrier();                                             \
  int b_ = 0;                                                               \
  for (int t_ = 0; t_ < (NT); ++t_, b_ ^= 1) {                              \
    PHASE(AG(b_,0), BG(b_,0), 0, 1,                                         \
          { if (t_+1 < (NT)) STAGE_A(b_^1, 1, 2*(t_+1)+1); }, {});          \
    PHASE(AG(b_,0), BG(b_,0), 4, 0,                                         \
          { if (t_+1 < (NT)) STAGE_B(b_^1, 1, 2*(t_+1)+1); }, {});          \
    PHASE(AG(b_,1), BG(b_,1), 0, 1,                                         \
          { if (t_+2 < (NT)) STAGE_A(b_, 0, 2*(t_+2)); }, {});              \
    PHASE(AG(b_,1), BG(b_,1), 4, 0,                                         \
          { if (t_+2 < (NT)) STAGE_B(b_, 0, 2*(t_+2)); },                   \
          { if (t_+2 < (NT)) VM4(); else VM0(); });                         \
  }                                                                         \
} while (0)

// ---------------- GEMM1: H = gelu(gather(Xb) @ W1b + b1) ----------------
__global__ __launch_bounds__(512) void gemm1_v6(
    const unsigned short* __restrict__ Xb, const unsigned short* __restrict__ W1b,
    const float* __restrict__ b1,
    const int* __restrict__ cnt, const int* __restrict__ offs,
    const int* __restrict__ tok_list,
    const int* __restrict__ blk_e, const int* __restrict__ blk_m,
    unsigned short* __restrict__ H)
{
  int e = blk_e[blockIdx.y];
  if (e < 0) return;
  int m0 = blk_m[blockIdx.y];
  int ce = cnt[e];
  int off = offs[e];
  int J = blockIdx.x;

  __shared__ __align__(16) char ldsb[131072];
  __shared__ int s_tok[256];

  int tid = threadIdx.x;
  if (tid < 256) {
    int idx = m0 + tid;
    s_tok[tid] = tok_list[e*NTOK + ((idx < ce) ? idx : (ce-1))];
  }
  __syncthreads();

  int l = tid & 63, w = tid >> 6;
  int wr = w >> 2, wc = w & 3;
  int q = l & 15, g = l >> 4;

  const char* asrc0; const char* asrc1;
  {
    int c0 = tid,        R0 = c0 >> 3, d0 = (c0 & 7) ^ (R0 & 7);
    int c1 = 512 + tid,  R1 = c1 >> 3, d1 = (c1 & 7) ^ (R1 & 7);
    asrc0 = (const char*)(Xb + (size_t)s_tok[(R0<<1)|(d0>>2)]*DDIM) + (d0 & 3)*16;
    asrc1 = (const char*)(Xb + (size_t)s_tok[(R1<<1)|(d1>>2)]*DDIM) + (d1 & 3)*16;
  }
  const int dstoff0 = tid*16, dstoff1 = tid*16 + 8192;
  const char* bsrc = (const char*)W1b + (size_t)((e*16 + J)*32) * 16384 + (size_t)tid*16;

  int RA = (wr*128 + q) >> 1, RB = (wc*64 + q) >> 1;
  int dq = ((q & 1) << 2) | g;
  const int aoff0 = RA*64 + (dq ^ (RA & 7))*8;
  const int boff0 = RB*64 + (dq ^ (RB & 7))*8;

  f32x4 acc[8][4];
#pragma unroll
  for (int mi = 0; mi < 8; ++mi)
#pragma unroll
    for (int ni = 0; ni < 4; ++ni) acc[mi][ni] = (f32x4){0.f,0.f,0.f,0.f};
  bf16x8 bfv[4];

  KLOOP(DDIM/64);

  // epilogue: bias+gelu, permuted H col order (phys = base + q*4 + ni)
  int n0 = J*256;
  float bias[4];
#pragma unroll
  for (int ni = 0; ni < 4; ++ni) bias[ni] = b1[(size_t)e*FDIM + n0 + wc*64 + ni*16 + q];
#pragma unroll
  for (int mi = 0; mi < 8; ++mi) {
#pragma unroll
    for (int j = 0; j < 4; ++j) {
      int r = wr*128 + mi*16 + g*4 + j;
      if (m0 + r >= ce) continue;
      u16x4 hv;
#pragma unroll
      for (int ni = 0; ni < 4; ++ni) {
        float h = acc[mi][ni][j] + bias[ni];
        hv[ni] = __builtin_bit_cast(unsigned short, (__bf16)gelu_tanh(h));
      }
      *(u16x4*)&H[(size_t)(off + m0 + r)*FDIM + n0 + wc*64 + q*4] = hv;
    }
  }
}

// ---------------- GEMM2: out[tok] += w * (H @ W2b + b2), split-K x2 -------------
__global__ __launch_bounds__(512) void gemm2_v6(
    const unsigned short* __restrict__ H, const unsigned short* __restrict__ W2b,
    const float* __restrict__ b2,
    const int* __restrict__ cnt, const int* __restrict__ offs,
    const int* __restrict__ tok_list, const float* __restrict__ wt_list,
    const int* __restrict__ blk_e, const int* __restrict__ blk_m,
    float* __restrict__ out)
{
  int e = blk_e[blockIdx.y];
  if (e < 0) return;
  int m0 = blk_m[blockIdx.y];
  int ce = cnt[e];
  int off = offs[e];
  int J = blockIdx.x;
  int s = blockIdx.z;                // K-split: phys H cols [s*2048, s*2048+2048)

  __shared__ __align__(16) char ldsb[131072];
  __shared__ int   s_tok[256];
  __shared__ float s_wt[256];

  int tid = threadIdx.x;
  if (tid < 256) {
    int idx = m0 + tid;
    int cidx = (idx < ce) ? idx : (ce-1);
    s_tok[tid] = tok_list[e*NTOK + cidx];
    s_wt[tid]  = (idx < ce) ? wt_list[e*NTOK + cidx] : 0.0f;
  }
  __syncthreads();

  int l = tid & 63, w = tid >> 6;
  int wr = w >> 2, wc = w & 3;
  int q = l & 15, g = l >> 4;

  const char* asrc0; const char* asrc1;
  {
    int c0 = tid,        R0 = c0 >> 3, d0 = (c0 & 7) ^ (R0 & 7);
    int c1 = 512 + tid,  R1 = c1 >> 3, d1 = (c1 & 7) ^ (R1 & 7);
    int r0 = (R0<<1)|(d0>>2), r1 = (R1<<1)|(d1>>2);
    int rr0 = (m0 + r0 < ce) ? r0 : (ce-1-m0);
    int rr1 = (m0 + r1 < ce) ? r1 : (ce-1-m0);
    asrc0 = (const char*)(H + (size_t)(off + m0 + rr0)*FDIM) + (d0 & 3)*16 + s*4096;
    asrc1 = (const char*)(H + (size_t)(off + m0 + rr1)*FDIM) + (d1 & 3)*16 + s*4096;
  }
  const int dstoff0 = tid*16, dstoff1 = tid*16 + 8192;
  const char* bsrc = (const char*)W2b + (size_t)((e*4 + J)*128 + s*64) * 16384 + (size_t)tid*16;

  int RA = (wr*128 + q) >> 1, RB = (wc*64 + q) >> 1;
  int dq = ((q & 1) << 2) | g;
  const int aoff0 = RA*64 + (dq ^ (RA & 7))*8;
  const int boff0 = RB*64 + (dq ^ (RB & 7))*8;

  f32x4 acc[8][4];
#pragma unroll
  for (int mi = 0; mi < 8; ++mi)
#pragma unroll
    for (int ni = 0; ni < 4; ++ni) acc[mi][ni] = (f32x4){0.f,0.f,0.f,0.f};
  bf16x8 bfv[4];

  KLOOP(FDIM/64/2);

  int n0 = J*256;
  float bias[4];
#pragma unroll
  for (int ni = 0; ni < 4; ++ni)
    bias[ni] = (s == 0) ? b2[(size_t)e*DDIM + n0 + wc*64 + ni*16 + q] : 0.0f;
#pragma unroll
  for (int mi = 0; mi < 8; ++mi) {
#pragma unroll
    for (int j = 0; j < 4; ++j) {
      int r = wr*128 + mi*16 + g*4 + j;
      if (m0 + r >= ce) continue;
      int tok = s_tok[r];
      float wt = s_wt[r];
      float* orow = out + (size_t)tok * DDIM;
#pragma unroll
      for (int ni = 0; ni < 4; ++ni) {
        float y = acc[mi][ni][j] + bias[ni];
        unsafeAtomicAdd(&orow[n0 + wc*64 + ni*16 + q], wt * y);
      }
    }
  }
}

// ---------------- launch ----------------
extern "C" void kernel_launch(void* const* d_in, const int* in_sizes, int n_in,
                              void* d_out, int out_size, void* d_ws, size_t ws_size,
                              hipStream_t stream)
{
  const float* x       = (const float*)d_in[0];
  const float* task    = (const float*)d_in[1];
  const float* alpha   = (const float*)d_in[2];
  const float* Wg_in   = (const float*)d_in[3];
  const float* bg_in   = (const float*)d_in[4];
  const float* Wg_task = (const float*)d_in[5];
  const float* bg_task = (const float*)d_in[6];
  const float* W1      = (const float*)d_in[7];
  const float* b1      = (const float*)d_in[8];
  const float* W2      = (const float*)d_in[9];
  const float* b2      = (const float*)d_in[10];
  float* out = (float*)d_out;

  char* ws = (char*)d_ws;
  int*   cnt      = (int*)(ws + 0);
  float* wsum     = (float*)(ws + 32);
  int*   offs     = (int*)(ws + 64);
  int*   blk_e    = (int*)(ws + 128);
  int*   blk_m    = (int*)(ws + 512);
  int*   tok_list = (int*)(ws + 4096);
  float* wt_list  = (float*)(ws + 4096 + NTOK*NEXP*4);
  unsigned short* H   = (unsigned short*)(ws + H_OFF);
  unsigned short* W1b = (unsigned short*)(ws + W1B_OFF);
  unsigned short* W2b = (unsigned short*)(ws + W2B_OFF);
  unsigned short* Xb  = (unsigned short*)(ws + XB_OFF);

  hipMemsetAsync(d_out, 0, (size_t)out_size * sizeof(float), stream);
  hipMemsetAsync(ws, 0, 128, stream);
  gate_kernel<<<NTOK/4, 256, 0, stream>>>(x, task, alpha, Wg_in, bg_in, Wg_task, bg_task,
                                          cnt, wsum, tok_list, wt_list);
  finalize_kernel<<<1, 64, 0, stream>>>(cnt, wsum, offs, out + (size_t)NTOK*DDIM, blk_e, blk_m);
  prep_x<<<NTOK*DDIM/2048, 256, 0, stream>>>(x, Xb);
  prep_w<false><<<dim3(16, 16, NEXP), 256, 0, stream>>>(W1, W1b, FDIM, 16, 16);
  prep_w<true ><<<dim3(64,  4, NEXP), 256, 0, stream>>>(W2, W2b, DDIM, 64, 4);
  gemm1_v6<<<dim3(16, MAXBLK), 512, 0, stream>>>(Xb, W1b, b1, cnt, offs, tok_list,
                                                 blk_e, blk_m, H);
  gemm2_v6<<<dim3(4, MAXBLK, 2), 512, 0, stream>>>(H, W2b, b2, cnt, offs, tok_list, wt_list,
                                                   blk_e, blk_m, out);
}